// Round 1
// baseline (114.813 us; speedup 1.0000x reference)
//
#include <hip/hip_runtime.h>

// LossUResidu: loss = mean_b,vox [ |A u - b| / mx * (1-f) ]
// Simplifies to: sum over img==0 voxels of |7pt-clamped-laplacian(u)| / mx_b, / (B*N).
// mx_b = max over voxels of dv(i)+dv(j)+dv(k) + (img!=0)*C, C = dx^2/eps_needle.

namespace {
constexpr int NDIM = 128;
constexpr int NPS = NDIM * NDIM * NDIM;   // per-sample voxels
constexpr int BATCH = 4;
constexpr int NV_PER_S = NPS / 4;         // 524288 float4-vectors per sample
constexpr int TOTALV = BATCH * NV_PER_S;  // 2097152
}

__global__ __launch_bounds__(64) void init_ws_k(double* sums, unsigned* maxb) {
    int t = threadIdx.x;
    if (t < BATCH) { sums[t] = 0.0; maxb[t] = 0u; }
}

__device__ __forceinline__ float dvf(int p) {
    return (p == 0 || p == NDIM - 1) ? 1.0f : 2.0f;
}

__global__ __launch_bounds__(256) void loss_main_k(
        const float* __restrict__ u, const float* __restrict__ img,
        double* __restrict__ sums, unsigned* __restrict__ maxb, float C) {
    int v = blockIdx.x * 256 + threadIdx.x;
    if (v >= TOTALV) return;
    int b   = v >> 19;                 // NV_PER_S = 2^19
    int rem = v & ((1 << 19) - 1);
    int i   = rem >> 12;               // 128 j-rows * 32 kvec = 4096 per i
    int j   = (rem >> 5) & 127;
    int k4  = (rem & 31) << 2;

    const float* ub = u   + (size_t)b * NPS;
    const float* gb = img + (size_t)b * NPS;
    int base = (i * NDIM + j) * NDIM + k4;

    float4 c  = *(const float4*)(ub + base);
    float lft = (k4 == 0)          ? c.x : ub[base - 1];
    float rgt = (k4 == NDIM - 4)   ? c.w : ub[base + 4];
    float4 jm = (j == 0)        ? c : *(const float4*)(ub + base - NDIM);
    float4 jp = (j == NDIM - 1) ? c : *(const float4*)(ub + base + NDIM);
    float4 im = (i == 0)        ? c : *(const float4*)(ub + base - NDIM * NDIM);
    float4 ip = (i == NDIM - 1) ? c : *(const float4*)(ub + base + NDIM * NDIM);
    float4 g4 = *(const float4*)(gb + base);

    float dij = dvf(i) + dvf(j);

    float cc[4] = {c.x, c.y, c.z, c.w};
    float zl[4] = {lft, c.x, c.y, c.z};
    float zr[4] = {c.y, c.z, c.w, rgt};
    float ym[4] = {jm.x, jm.y, jm.z, jm.w};
    float yp[4] = {jp.x, jp.y, jp.z, jp.w};
    float xm[4] = {im.x, im.y, im.z, im.w};
    float xp[4] = {ip.x, ip.y, ip.z, ip.w};
    float gg[4] = {g4.x, g4.y, g4.z, g4.w};

    float sum = 0.0f, mx = 0.0f;
#pragma unroll
    for (int t = 0; t < 4; ++t) {
        float lap = (xm[t] + xp[t]) + (ym[t] + yp[t]) + (zl[t] + zr[t]) - 6.0f * cc[t];
        bool needle = (gg[t] != 0.0f);   // f==1 (img is exactly -1/0/+1)
        if (!needle) sum += fabsf(lap);  // |Au - b|, b==0 and f_div_eps==0 here
        float diag = dij + dvf(k4 + t) + (needle ? C : 0.0f);
        mx = fmaxf(mx, diag);
    }

    // wave-64 tree reduce
#pragma unroll
    for (int off = 32; off > 0; off >>= 1) {
        sum += __shfl_down(sum, off);
        mx = fmaxf(mx, __shfl_down(mx, off));
    }
    __shared__ float ssum[4];
    __shared__ float smax[4];
    int wave = threadIdx.x >> 6, lane = threadIdx.x & 63;
    if (lane == 0) { ssum[wave] = sum; smax[wave] = mx; }
    __syncthreads();
    if (threadIdx.x == 0) {
        float S = (ssum[0] + ssum[1]) + (ssum[2] + ssum[3]);
        float M = fmaxf(fmaxf(smax[0], smax[1]), fmaxf(smax[2], smax[3]));
        atomicAdd(&sums[b], (double)S);         // block spans exactly one sample
        atomicMax(&maxb[b], __float_as_uint(M)); // all values > 0: uint order == float order
    }
}

__global__ __launch_bounds__(64) void finalize_k(const double* __restrict__ sums,
                                                 const unsigned* __restrict__ maxb,
                                                 float* __restrict__ out) {
    if (threadIdx.x == 0 && blockIdx.x == 0) {
        double tot = 0.0;
        for (int b = 0; b < BATCH; ++b)
            tot += sums[b] / (double)__uint_as_float(maxb[b]);
        out[0] = (float)(tot / ((double)BATCH * (double)NPS));  // WEIGHT_RESIDU == 1
    }
}

extern "C" void kernel_launch(void* const* d_in, const int* in_sizes, int n_in,
                              void* d_out, int out_size, void* d_ws, size_t ws_size,
                              hipStream_t stream) {
    const float* u   = (const float*)d_in[0];  // "output" (the field being solved)
    // d_in[1] = "gt": only shape is used by the reference -> never read
    const float* img = (const float*)d_in[2];  // "input" trinary field
    float* out = (float*)d_out;

    double* sums   = (double*)d_ws;
    unsigned* maxb = (unsigned*)((char*)d_ws + 64);

    const double dx = 2.0 / (NDIM - 1);
    const float  C  = (float)((dx * dx) / 1e-6);  // dx2 / EPS_NEEDLE ~= 248.0005

    hipLaunchKernelGGL(init_ws_k, dim3(1), dim3(64), 0, stream, sums, maxb);
    hipLaunchKernelGGL(loss_main_k, dim3(TOTALV / 256), dim3(256), 0, stream,
                       u, img, sums, maxb, C);
    hipLaunchKernelGGL(finalize_k, dim3(1), dim3(64), 0, stream, sums, maxb, out);
}

// Round 2
// 23.324 us; speedup vs baseline: 4.9226x; 4.9226x over previous
//
#include <hip/hip_runtime.h>

// LossUResidu: loss = mean_{b,vox} [ |A u - b| / mx_b * (1-f) ]
// Simplifies to: sum over img==0 voxels of |7pt clamped-neighbor laplacian(u)| / mx_b, / (B*N).
// mx_b = max over voxels of dv(i)+dv(j)+dv(k) + (img!=0)*C, C = dx^2/eps_needle.
// gt is never read (shape only). a1 = a2 = 1 (cubic grid).

namespace {
constexpr int NDIM  = 128;
constexpr int NPS   = NDIM * NDIM * NDIM;  // 2^21 voxels per sample
constexpr int BATCH = 4;
constexpr int BLOCKS_PER_S = 512;          // per-sample blocks
constexpr int NBLOCKS = BATCH * BLOCKS_PER_S;          // 2048
constexpr int THREADS_PER_S = BLOCKS_PER_S * 256;      // 131072
constexpr int ITERS = (NPS / 4) / THREADS_PER_S;       // 4 float4-iters per thread
}

__global__ __launch_bounds__(256) void loss_main_k(
        const float* __restrict__ u, const float* __restrict__ img,
        float* __restrict__ psum, float* __restrict__ pmax, float C) {
    int blk  = blockIdx.x;
    int b    = blk >> 9;                   // / BLOCKS_PER_S
    int q    = blk & (BLOCKS_PER_S - 1);
    int tidS = q * 256 + threadIdx.x;      // thread index within sample [0, 131072)

    const float* ub = u   + (size_t)b * NPS;
    const float* gb = img + (size_t)b * NPS;

    float sum = 0.0f, mx = 0.0f;

#pragma unroll
    for (int s = 0; s < ITERS; ++s) {
        int vid = tidS + s * THREADS_PER_S;     // float4 index within sample
        int i   = vid >> 12;
        int j   = (vid >> 5) & 127;
        int k4  = (vid & 31) << 2;
        int base = (i * NDIM + j) * NDIM + k4;

        // branch-free clamped-neighbor offsets (clamp -> reads center, matching
        // the Neumann boundary fix)
        int oim = (i == 0)        ? 0 : -NDIM * NDIM;
        int oip = (i == NDIM - 1) ? 0 :  NDIM * NDIM;
        int ojm = (j == 0)        ? 0 : -NDIM;
        int ojp = (j == NDIM - 1) ? 0 :  NDIM;
        int okl = (k4 == 0)        ? 0 : -1;
        int okr = (k4 == NDIM - 4) ? 3 :  4;

        float4 c  = *(const float4*)(ub + base);
        float4 im = *(const float4*)(ub + base + oim);
        float4 ip = *(const float4*)(ub + base + oip);
        float4 jm = *(const float4*)(ub + base + ojm);
        float4 jp = *(const float4*)(ub + base + ojp);
        float  lf = ub[base + okl];
        float  rg = ub[base + okr];
        float4 g4 = *(const float4*)(gb + base);

        float dij = ((i == 0 || i == NDIM - 1) ? 1.0f : 2.0f)
                  + ((j == 0 || j == NDIM - 1) ? 1.0f : 2.0f);

        float cc[4] = {c.x, c.y, c.z, c.w};
        float zl[4] = {lf, c.x, c.y, c.z};
        float zr[4] = {c.y, c.z, c.w, rg};
        float ym[4] = {jm.x, jm.y, jm.z, jm.w};
        float yp[4] = {jp.x, jp.y, jp.z, jp.w};
        float xm[4] = {im.x, im.y, im.z, im.w};
        float xp[4] = {ip.x, ip.y, ip.z, ip.w};
        float gg[4] = {g4.x, g4.y, g4.z, g4.w};

#pragma unroll
        for (int t = 0; t < 4; ++t) {
            float lap = (xm[t] + xp[t]) + (ym[t] + yp[t]) + (zl[t] + zr[t]) - 6.0f * cc[t];
            bool needle = (gg[t] != 0.0f);         // img is exactly -1/0/+1
            if (!needle) sum += fabsf(lap);        // |Au-b|: b==0, f_div_eps==0 here
            float dk = (k4 + t == 0 || k4 + t == NDIM - 1) ? 1.0f : 2.0f;
            float diag = dij + dk + (needle ? C : 0.0f);
            mx = fmaxf(mx, diag);
        }
    }

    // wave-64 tree reduce, then cross-wave via LDS
#pragma unroll
    for (int off = 32; off > 0; off >>= 1) {
        sum += __shfl_down(sum, off);
        mx = fmaxf(mx, __shfl_down(mx, off));
    }
    __shared__ float ssum[4], smax[4];
    int wave = threadIdx.x >> 6, lane = threadIdx.x & 63;
    if (lane == 0) { ssum[wave] = sum; smax[wave] = mx; }
    __syncthreads();
    if (threadIdx.x == 0) {
        psum[blk] = (ssum[0] + ssum[1]) + (ssum[2] + ssum[3]);
        pmax[blk] = fmaxf(fmaxf(smax[0], smax[1]), fmaxf(smax[2], smax[3]));
    }
}

__global__ __launch_bounds__(256) void finalize_k(const float* __restrict__ psum,
                                                  const float* __restrict__ pmax,
                                                  float* __restrict__ out) {
    // one wave per sample; lane reads 8 partials (512/64)
    int wave = threadIdx.x >> 6, lane = threadIdx.x & 63;
    double s = 0.0; float m = 0.0f;
    int base = wave * BLOCKS_PER_S;
#pragma unroll
    for (int r = 0; r < BLOCKS_PER_S / 64; ++r) {
        int idx = base + r * 64 + lane;
        s += (double)psum[idx];
        m = fmaxf(m, pmax[idx]);
    }
#pragma unroll
    for (int off = 32; off > 0; off >>= 1) {
        s += __shfl_down(s, off);
        m = fmaxf(m, __shfl_down(m, off));
    }
    __shared__ double ws[4]; __shared__ float wm[4];
    if (lane == 0) { ws[wave] = s; wm[wave] = m; }
    __syncthreads();
    if (threadIdx.x == 0) {
        double tot = 0.0;
        for (int b = 0; b < BATCH; ++b) tot += ws[b] / (double)wm[b];
        out[0] = (float)(tot / ((double)BATCH * (double)NPS));  // WEIGHT_RESIDU == 1
    }
}

extern "C" void kernel_launch(void* const* d_in, const int* in_sizes, int n_in,
                              void* d_out, int out_size, void* d_ws, size_t ws_size,
                              hipStream_t stream) {
    const float* u   = (const float*)d_in[0];  // "output" (field)
    // d_in[1] = "gt": shape-only, never read
    const float* img = (const float*)d_in[2];  // trinary field
    float* out = (float*)d_out;

    float* psum = (float*)d_ws;
    float* pmax = psum + NBLOCKS;

    const double dx = 2.0 / (NDIM - 1);
    const float  C  = (float)((dx * dx) / 1e-6);  // ~248.0005

    hipLaunchKernelGGL(loss_main_k, dim3(NBLOCKS), dim3(256), 0, stream,
                       u, img, psum, pmax, C);
    hipLaunchKernelGGL(finalize_k, dim3(1), dim3(256), 0, stream, psum, pmax, out);
}

// Round 3
// 20.782 us; speedup vs baseline: 5.5247x; 1.1223x over previous
//
#include <hip/hip_runtime.h>

// LossUResidu: loss = mean_{b,vox} [ |A u - b| / mx_b * (1-f) ]
// = [ sum over img==0 voxels of |7pt clamped-neighbor laplacian(u)| ] / mx_b / (B*N).
// mx_b = max over voxels of dv(i)+dv(j)+dv(k) + (img!=0)*C, C = dx^2/eps_needle.
// gt never read. a1 = a2 = 1 (cubic grid).

namespace {
constexpr int NDIM  = 128;
constexpr int PL    = NDIM * NDIM;         // plane stride (floats)
constexpr int NPS   = NDIM * NDIM * NDIM;  // 2^21 voxels per sample
constexpr int BATCH = 4;
constexpr int BLOCKS_PER_S = 512;
constexpr int NBLOCKS = BATCH * BLOCKS_PER_S;  // 2048
constexpr int ITERS = 4;                   // i-planes strided by 32 per thread
}

__global__ __launch_bounds__(256) void loss_main_k(
        const float* __restrict__ u, const float* __restrict__ img,
        float* __restrict__ psum, float* __restrict__ pmax, float C) {
    int blk = blockIdx.x;
    int b   = blk >> 9;
    int q   = blk & (BLOCKS_PER_S - 1);
    int tid = q * 256 + threadIdx.x;       // [0, 131072) within sample
    int i0  = tid >> 12;                   // [0, 32)
    int j   = (tid >> 5) & 127;
    int k4  = (tid & 31) << 2;

    const float* ub = u   + (size_t)b * NPS;
    const float* gb = img + (size_t)b * NPS;
    int base0 = (i0 * NDIM + j) * NDIM + k4;

    // per-thread invariants (never change across iters)
    int ojm = (j == 0)        ? 0 : -NDIM;
    int ojp = (j == NDIM - 1) ? 0 :  NDIM;
    float dj  = (j == 0 || j == NDIM - 1) ? 1.0f : 2.0f;
    float dkt[4] = { (k4 == 0) ? 1.0f : 2.0f, 2.0f, 2.0f,
                     (k4 == NDIM - 4) ? 1.0f : 2.0f };

    // ---- issue ALL loads up front (max MLP); static indices only ----
    float4 c[ITERS], xm[ITERS], xp[ITERS], jm[ITERS], jp[ITERS], g[ITERS];
#pragma unroll
    for (int s = 0; s < ITERS; ++s) {
        int base = base0 + s * 32 * PL;
        int oim = (s == 0 && i0 == 0)         ? 0 : -PL;  // only s==0 can touch i=0
        int oip = (s == ITERS - 1 && i0 == 31) ? 0 :  PL; // only s==3 can touch i=127
        c[s]  = *(const float4*)(ub + base);
        xm[s] = *(const float4*)(ub + base + oim);
        xp[s] = *(const float4*)(ub + base + oip);
        jm[s] = *(const float4*)(ub + base + ojm);
        jp[s] = *(const float4*)(ub + base + ojp);
        g[s]  = *(const float4*)(gb + base);
    }

    float sum = 0.0f, mx = 0.0f;
#pragma unroll
    for (int s = 0; s < ITERS; ++s) {
        float di = 2.0f;
        if (s == 0         && i0 == 0)  di = 1.0f;
        if (s == ITERS - 1 && i0 == 31) di = 1.0f;
        float dij = di + dj;

        // k-neighbors across lanes (rows are 32-lane aligned; boundary lanes clamped)
        float lf_raw = __shfl_up(c[s].w, 1);
        float rg_raw = __shfl_down(c[s].x, 1);

        float cc[4] = {c[s].x, c[s].y, c[s].z, c[s].w};
        float zl[4] = {(k4 == 0) ? c[s].x : lf_raw, c[s].x, c[s].y, c[s].z};
        float zr[4] = {c[s].y, c[s].z, c[s].w, (k4 == NDIM - 4) ? c[s].w : rg_raw};
        float ym[4] = {jm[s].x, jm[s].y, jm[s].z, jm[s].w};
        float yp[4] = {jp[s].x, jp[s].y, jp[s].z, jp[s].w};
        float im[4] = {xm[s].x, xm[s].y, xm[s].z, xm[s].w};
        float ip[4] = {xp[s].x, xp[s].y, xp[s].z, xp[s].w};
        float gg[4] = {g[s].x, g[s].y, g[s].z, g[s].w};

#pragma unroll
        for (int t = 0; t < 4; ++t) {
            float lap = (im[t] + ip[t]) + (ym[t] + yp[t]) + (zl[t] + zr[t]) - 6.0f * cc[t];
            bool needle = (gg[t] != 0.0f);           // img is exactly -1/0/+1
            sum += needle ? 0.0f : fabsf(lap);       // |Au-b|: b==0, f_div_eps==0 here
            float diag = dij + dkt[t] + (needle ? C : 0.0f);
            mx = fmaxf(mx, diag);
        }
    }

    // wave-64 tree reduce, then cross-wave via LDS
#pragma unroll
    for (int off = 32; off > 0; off >>= 1) {
        sum += __shfl_down(sum, off);
        mx = fmaxf(mx, __shfl_down(mx, off));
    }
    __shared__ float ssum[4], smax[4];
    int wave = threadIdx.x >> 6, lane = threadIdx.x & 63;
    if (lane == 0) { ssum[wave] = sum; smax[wave] = mx; }
    __syncthreads();
    if (threadIdx.x == 0) {
        psum[blk] = (ssum[0] + ssum[1]) + (ssum[2] + ssum[3]);
        pmax[blk] = fmaxf(fmaxf(smax[0], smax[1]), fmaxf(smax[2], smax[3]));
    }
}

__global__ __launch_bounds__(256) void finalize_k(const float* __restrict__ psum,
                                                  const float* __restrict__ pmax,
                                                  float* __restrict__ out) {
    // one wave per sample; lane reads 8 partials (512/64)
    int wave = threadIdx.x >> 6, lane = threadIdx.x & 63;
    double s = 0.0; float m = 0.0f;
    int base = wave * BLOCKS_PER_S;
#pragma unroll
    for (int r = 0; r < BLOCKS_PER_S / 64; ++r) {
        int idx = base + r * 64 + lane;
        s += (double)psum[idx];
        m = fmaxf(m, pmax[idx]);
    }
#pragma unroll
    for (int off = 32; off > 0; off >>= 1) {
        s += __shfl_down(s, off);
        m = fmaxf(m, __shfl_down(m, off));
    }
    __shared__ double ws[4]; __shared__ float wm[4];
    if (lane == 0) { ws[wave] = s; wm[wave] = m; }
    __syncthreads();
    if (threadIdx.x == 0) {
        double tot = 0.0;
        for (int b = 0; b < BATCH; ++b) tot += ws[b] / (double)wm[b];
        out[0] = (float)(tot / ((double)BATCH * (double)NPS));  // WEIGHT_RESIDU == 1
    }
}

extern "C" void kernel_launch(void* const* d_in, const int* in_sizes, int n_in,
                              void* d_out, int out_size, void* d_ws, size_t ws_size,
                              hipStream_t stream) {
    const float* u   = (const float*)d_in[0];  // "output" (field)
    // d_in[1] = "gt": shape-only, never read
    const float* img = (const float*)d_in[2];  // trinary field
    float* out = (float*)d_out;

    float* psum = (float*)d_ws;
    float* pmax = psum + NBLOCKS;

    const double dx = 2.0 / (NDIM - 1);
    const float  C  = (float)((dx * dx) / 1e-6);  // ~248.0005

    hipLaunchKernelGGL(loss_main_k, dim3(NBLOCKS), dim3(256), 0, stream,
                       u, img, psum, pmax, C);
    hipLaunchKernelGGL(finalize_k, dim3(1), dim3(256), 0, stream, psum, pmax, out);
}